// Round 9
// baseline (505.001 us; speedup 1.0000x reference)
//
#include <hip/hip_runtime.h>
#include <cstdint>
#include <cstddef>

// ---- problem constants ----
#define BQ   8
#define NP   512
#define GQ   16
#define PP   528      // NP + GQ
#define RT   4224     // BQ * PP
#define MPAD 4352     // RT padded to 34 row-blocks of 128
#define CC   91
#define FEATD 12544
#define REPD 1024
#define NH   512      // padded head output cols (455 used: 91 cls + 364 box)
#define NHU  455
#define BETA (1.0f/9.0f)
#define WSC  64.0f    // fp8 weight pre-scale (exact pow2; undone in reduce/loss)

typedef float f32x4 __attribute__((ext_vector_type(4)));
typedef int   v8i  __attribute__((ext_vector_type(8)));
typedef float v16f __attribute__((ext_vector_type(16)));

__device__ __forceinline__ unsigned short f2bf(float f) {
  unsigned int x = __float_as_uint(f);
  unsigned int r = (x + 0x7fffu + ((x >> 16) & 1u)) >> 16;
  return (unsigned short)r;
}
__device__ __forceinline__ float bf2f(unsigned short u) {
  return __uint_as_float((unsigned int)u << 16);
}

// async global->LDS DMA, 16 B per lane; HW writes lane L to base + L*16.
__device__ __forceinline__ void ld_lds16(const void* g, void* l) {
  __builtin_amdgcn_global_load_lds(
      (const __attribute__((address_space(1))) void*)g,
      (__attribute__((address_space(3))) void*)l, 16, 0, 0);
}

// ---- tile-image layout --------------------------------------------------
// Image: 128-row x 64-kbyte tile = 8192 B, tiles ordered [rowblk][ktile].
// Within a tile: region (row>>5)&3 (2048 B), then [kc=(kb>>4)&3][r=row&31][16B].
__device__ __forceinline__ size_t img_off(int row, int kb, int KT) {
  return (size_t)((row >> 7) * KT + (kb >> 6)) * 8192
       + (size_t)((((row >> 5) & 3) << 11) + (((kb >> 4) & 3) << 9)
                  + ((row & 31) << 4) + (kb & 15));
}

// ---- workspace layout (bytes) ----
constexpr size_t O_W1T = 0;
constexpr size_t SZ_W1T = (size_t)FEATD * REPD;             // W1^T fp8 image
constexpr size_t O_W2T = O_W1T + SZ_W1T;
constexpr size_t SZ_W2T = (size_t)REPD * REPD;              // W2^T fp8 image
constexpr size_t O_WH  = O_W2T + SZ_W2T;
constexpr size_t SZ_WH = (size_t)NH * REPD;                 // [Wcls|Wbox]^T fp8 image
constexpr size_t O_BH  = O_WH + SZ_WH;
constexpr size_t SZ_BH = (size_t)NH * 4;
constexpr size_t O_X1  = O_BH + SZ_BH;
constexpr size_t SZ_X1 = (size_t)MPAD * REPD;               // x1 fp8 image (padded)
constexpr size_t O_X2  = O_X1 + SZ_X1;                      // x2 fp8 image (padded)
constexpr size_t O_LAB = O_X2 + SZ_X1;
constexpr size_t O_TGT = O_LAB + (size_t)RT * 4;
constexpr size_t O_NLL = O_TGT + (size_t)RT * 16;
constexpr size_t O_VC  = O_NLL + (size_t)RT * 4;
constexpr size_t O_SL1 = O_VC + (size_t)RT * 4;
constexpr size_t O_PART = ((O_SL1 + (size_t)RT * 4) + 255) & ~(size_t)255;
constexpr size_t SZ_PART = (size_t)4 * MPAD * REPD * 2;     // bf16 partials (padded M)
constexpr size_t O_F8 = O_PART + SZ_PART;                   // fp8 feature image, 54.6 MB

// ===== prep_cv v3: contiguous-read feature convert (R8-proven) ==========
#define NB_CV ((MPAD/32)*(FEATD/256))    // 136*49 = 6664
__global__ void prep_cv(const float* __restrict__ feat, unsigned char* __restrict__ feat8) {
  __shared__ unsigned char lb[32 * 264];
  const int b = blockIdx.x, t = threadIdx.x;
  const int yb = b / (FEATD / 256), kc4 = b % (FEATD / 256);
  const int w = t >> 6, L = t & 63;
  const int row0 = yb * 32;
  if (row0 < RT) {
#pragma unroll
    for (int i = 0; i < 8; ++i) {
      int r = w * 8 + i;
      float4 f = *(const float4*)(feat + (size_t)(row0 + r) * FEATD + kc4 * 256 + L * 4);
      unsigned int pk = (unsigned int)__builtin_amdgcn_cvt_pk_fp8_f32(f.x, f.y, 0, false);
      pk = (unsigned int)__builtin_amdgcn_cvt_pk_fp8_f32(f.z, f.w, (int)pk, true);
      *(unsigned int*)&lb[r * 264 + L * 4] = pk;
    }
  } else {                               // pad rows 4224..4351 -> zeros
#pragma unroll
    for (int i = 0; i < 8; ++i)
      *(unsigned int*)&lb[(w * 8 + i) * 264 + L * 4] = 0u;
  }
  __syncthreads();
  const size_t base = ((size_t)(yb >> 2) * (FEATD / 64) + kc4 * 4) * 8192
                    + (size_t)(yb & 3) * 2048;
#pragma unroll
  for (int q = 0; q < 2; ++q) {
    int s = t + 256 * q;
    int tile = s >> 7, kc = (s >> 5) & 3, r = s & 31;
    int4 v = *(const int4*)&lb[r * 264 + tile * 64 + kc * 16];
    *(int4*)&feat8[base + (size_t)tile * 8192 + kc * 512 + r * 16] = v;
  }
}

// ===== prep_w: weight transpose-convert(x64) -> tile image ==============
__device__ __forceinline__ void tr128(const float* __restrict__ in, unsigned char* __restrict__ out,
                                      int K, int N, int row_off, int KT,
                                      int bx, int by, int t, float (*tile)[36]) {
  const int n0 = bx * 32, k0 = by * 128;
  const int n4 = t & 7, kr = t >> 3;       // kr 0..31
  if (n0 + 32 <= N) {
#pragma unroll
    for (int i = 0; i < 4; ++i) {
      int k = k0 + kr + i * 32;
      float4 f = *(const float4*)&in[(size_t)k * N + n0 + n4 * 4];
      *(float4*)&tile[kr + i * 32][n4 * 4] = f;
    }
  } else {
#pragma unroll
    for (int i = 0; i < 4; ++i) {
      int k = k0 + kr + i * 32;
#pragma unroll
      for (int j = 0; j < 4; ++j) {
        int n = n0 + n4 * 4 + j;
        tile[kr + i * 32][n4 * 4 + j] = (n < N) ? in[(size_t)k * N + n] : 0.0f;
      }
    }
  }
  __syncthreads();
  const int rn = t & 31, kc = t >> 5;      // kc 0..7 (16 k each)
  const int n = n0 + rn;
  if (n < N) {
    unsigned int pk[4];
#pragma unroll
    for (int q = 0; q < 4; ++q) {
      float f0 = tile[kc * 16 + q * 4 + 0][rn] * WSC;
      float f1 = tile[kc * 16 + q * 4 + 1][rn] * WSC;
      float f2 = tile[kc * 16 + q * 4 + 2][rn] * WSC;
      float f3 = tile[kc * 16 + q * 4 + 3][rn] * WSC;
      unsigned int r = (unsigned int)__builtin_amdgcn_cvt_pk_fp8_f32(f0, f1, 0, false);
      pk[q] = (unsigned int)__builtin_amdgcn_cvt_pk_fp8_f32(f2, f3, (int)r, true);
    }
    int4 v; v.x = (int)pk[0]; v.y = (int)pk[1]; v.z = (int)pk[2]; v.w = (int)pk[3];
    *(int4*)&out[img_off(n + row_off, k0 + kc * 16, KT)] = v;
  }
}

#define NBW1 ((REPD/32)*(FEATD/128))     // 3136
#define NBW2 ((REPD/32)*(REPD/128))      // 256
#define NBWC (3*(REPD/128))              // 24
#define NBWB (12*(REPD/128))             // 96
#define NB_PW (NBW1+NBW2+NBWC+NBWB)      // 3512

__global__ void prep_w(const float* __restrict__ W1, const float* __restrict__ W2,
                       const float* __restrict__ Wcls, const float* __restrict__ Wbox,
                       unsigned char* __restrict__ W1t, unsigned char* __restrict__ W2t,
                       unsigned char* __restrict__ Wh) {
  __shared__ float tile[128][36];
  int b = blockIdx.x, t = threadIdx.x;
  if (b < NBW1) { tr128(W1, W1t, FEATD, REPD, 0, FEATD/64, b % 32, b / 32, t, tile); return; }
  b -= NBW1;
  if (b < NBW2) { tr128(W2, W2t, REPD, REPD, 0, REPD/64, b % 32, b / 32, t, tile); return; }
  b -= NBW2;
  if (b < NBWC) { tr128(Wcls, Wh, REPD, CC, 0, REPD/64, b % 3, b / 3, t, tile); return; }
  b -= NBWC;
  tr128(Wbox, Wh, REPD, 4 * CC, CC, REPD/64, b % 12, b / 12, t, tile);
}

// ===== prep_misc: head pad/bias init + matcher/encode ===================
#define NB_HI 230
#define NB_MT 17
#define NB_MISC (NB_HI+NB_MT)
__global__ void prep_misc(const float* __restrict__ bcls, const float* __restrict__ bbox,
                          const float* __restrict__ proposals, const float* __restrict__ gt_boxes,
                          const int* __restrict__ gt_labels,
                          unsigned char* __restrict__ Wh, float* __restrict__ bh,
                          int* __restrict__ labels, float* __restrict__ tgts) {
  int b = blockIdx.x, t = threadIdx.x;
  if (b < NB_HI) {
    int idx = b * 256 + t;
    const int npad = (NH - NHU) * REPD;   // 58368 fp8 zeros (rows 455..511)
    if (idx < npad) {
      int row = NHU + (idx >> 10), k = idx & 1023;
      Wh[img_off(row, k, REPD/64)] = 0;
    } else {
      int i2 = idx - npad;
      if (i2 < NH) bh[i2] = (i2 < CC) ? bcls[i2] : (i2 < NHU ? bbox[i2 - CC] : 0.0f);
    }
    return;
  }
  b -= NB_HI;
  int r = b * 256 + t;
  if (r >= RT) return;
  int bi_ = r / PP, p = r % PP;
  float x0, y0, x1, y1;
  if (p < NP) {
    const float* qq = proposals + ((size_t)bi_ * NP + p) * 4;
    x0 = qq[0]; y0 = qq[1]; x1 = qq[2]; y1 = qq[3];
  } else {
    const float* qq = gt_boxes + ((size_t)bi_ * GQ + (p - NP)) * 4;
    x0 = qq[0]; y0 = qq[1]; x1 = qq[2]; y1 = qq[3];
  }
  float ap = (x1 - x0) * (y1 - y0);
  float best = -1.0f; int bg = 0;
#pragma unroll
  for (int g = 0; g < GQ; ++g) {
    const float* gb = gt_boxes + ((size_t)bi_ * GQ + g) * 4;
    float gx0 = gb[0], gy0 = gb[1], gx1 = gb[2], gy1 = gb[3];
    float ag = (gx1 - gx0) * (gy1 - gy0);
    float iw = fmaxf(fminf(gx1, x1) - fmaxf(gx0, x0), 0.0f);
    float ih = fmaxf(fminf(gy1, y1) - fmaxf(gy0, y0), 0.0f);
    float inter = iw * ih;
    float iou = inter / (ag + ap - inter);
    if (iou > best) { best = iou; bg = g; }   // strict > keeps first max (jnp.argmax)
  }
  int lab = gt_labels[bi_ * GQ + bg];
  if (best < 0.5f) lab = 0;    // FG==BG==0.5 -> ignore band empty
  labels[r] = lab;
  const float* gb = gt_boxes + ((size_t)bi_ * GQ + bg) * 4;
  float ew = x1 - x0, eh = y1 - y0;
  float ex = x0 + 0.5f * ew, ey = y0 + 0.5f * eh;
  float gw = gb[2] - gb[0], gh = gb[3] - gb[1];
  float gx = gb[0] + 0.5f * gw, gy = gb[1] + 0.5f * gh;
  tgts[r * 4 + 0] = 10.0f * (gx - ex) / ew;
  tgts[r * 4 + 1] = 10.0f * (gy - ey) / eh;
  tgts[r * 4 + 2] = 5.0f * logf(gw / ew);
  tgts[r * 4 + 3] = 5.0f * logf(gh / eh);
}

// ---- MX-scaled fp8 GEMM, 128x256 tile, BK=64, dbuf, counted vmcnt(3) ----
// Staged bytes scale as (1/BM + 1/BN): 128x256 cuts total staging 25% vs
// 128^2 (958 -> 718 MB across the 3 GEMMs) while keeping the PROVEN 64-VGPR
// per-wave geometry (acc[2][2], 64x64 quadrant per wave) that R7's 256^2
// violated (spill -> 1.19 GB scratch). 8 waves (512 thr) as 2(M) x 4(N).
// LDS: A 2x8 KB + B 2x16 KB = 48 KB -> 2 blocks/CU (96 KB), 4 waves/SIMD,
// launch_bounds(512,4) -> VGPR cap 128 (body is 88 in R6). 3 DMA/wave/iter.
__global__ __launch_bounds__(512, 4)
void gemm_f8(const unsigned char* __restrict__ Aimg, const unsigned char* __restrict__ Bimg,
             unsigned short* __restrict__ P, int Mp, int Nc, int KT, int nkt,
             int n_nblk, int n_my, int npairs) {
  __shared__ unsigned char As[2 * 8192];
  __shared__ unsigned char Bs[2 * 16384];

  const int g = blockIdx.x;
  const int xcd = g & 7;
  const int kix = g >> 3;
  const int n  = kix % n_nblk;
  const int pi = kix / n_nblk;
  const int p  = pi * 8 + xcd;
  if (p >= npairs) return;                 // uniform dummy exit, before any barrier
  const int y  = p % n_my;
  const int kz = p / n_my;
  const int m0 = y * 128, n0 = n * 256;

  const int tid = threadIdx.x;
  const int w = tid >> 6, L = tid & 63;    // w 0..7
  const int l31 = L & 31, h = L >> 5;
  const int mw = w >> 2, nw = w & 3;       // wave grid 2(M) x 4(N)

  const int kt0 = kz * nkt;
  // staging: wave w stages A chunk w (1 KB) + B chunks w and w+8 (1 KB each)
  const unsigned char* gA  = Aimg + ((size_t)y * KT + kt0) * 8192 + w * 1024 + L * 16;
  const unsigned char* gB0 = Bimg + ((size_t)(2 * n) * KT + kt0) * 8192 + w * 1024 + L * 16;
  const unsigned char* gB1 = Bimg + ((size_t)(2 * n + 1) * KT + kt0) * 8192 + w * 1024 + L * 16;
  const int lwA = w * 1024;
  const int lwB0 = w * 1024, lwB1 = 8192 + w * 1024;

#define STAGE(it, ba, bb) do {                                  \
    const size_t _go = (size_t)(it) * 8192;                     \
    ld_lds16(gA  + _go, &As[(ba) + lwA]);                       \
    ld_lds16(gB0 + _go, &Bs[(bb) + lwB0]);                      \
    ld_lds16(gB1 + _go, &Bs[(bb) + lwB1]);                      \
  } while (0)

  // fragments: A rows mw*64 + i*32 + l31; B cols nw*64 + j*32 + l31
  int aoff[2], boff[2];
#pragma unroll
  for (int i = 0; i < 2; ++i)
    aoff[i] = ((mw * 2 + i) << 11) + (h << 10) + (l31 << 4);
#pragma unroll
  for (int j = 0; j < 2; ++j) {
    int c5 = nw * 2 + j;                   // col>>5 index, 0..7
    boff[j] = (c5 >> 2) * 8192 + ((c5 & 3) << 11) + (h << 10) + (l31 << 4);
  }

  STAGE(0, 0, 0);                           // prologue: tile 0 -> buffer 0

  v16f acc[2][2] = {};
  int cur = 0;
  for (int it = 0; it < nkt; ++it) {
    const int ba = cur * 8192, bb = cur * 16384;
    if (it + 1 < nkt) {
      STAGE(it + 1, ba ^ 8192, bb ^ 16384); // next tile's 3 DMA stay in flight
      asm volatile("s_waitcnt vmcnt(3)" ::: "memory");
    } else {
      asm volatile("s_waitcnt vmcnt(0)" ::: "memory");
    }
    __builtin_amdgcn_sched_barrier(0);
    __builtin_amdgcn_s_barrier();           // tile staged for all waves

    v8i a[2], b[2];
#pragma unroll
    for (int i = 0; i < 2; ++i) {
      int4 alo = *(const int4*)&As[ba + aoff[i]];
      int4 ahi = *(const int4*)&As[ba + aoff[i] + 512];
      a[i] = (v8i){alo.x, alo.y, alo.z, alo.w, ahi.x, ahi.y, ahi.z, ahi.w};
      int4 blo = *(const int4*)&Bs[bb + boff[i]];
      int4 bhi = *(const int4*)&Bs[bb + boff[i] + 512];
      b[i] = (v8i){blo.x, blo.y, blo.z, blo.w, bhi.x, bhi.y, bhi.z, bhi.w};
    }
#pragma unroll
    for (int i = 0; i < 2; ++i)
#pragma unroll
      for (int j = 0; j < 2; ++j)
        acc[i][j] = __builtin_amdgcn_mfma_scale_f32_32x32x64_f8f6f4(
            a[i], b[j], acc[i][j], 0, 0, 0, 127, 0, 127);  // fp8/fp8, scales=2^0

    asm volatile("s_waitcnt lgkmcnt(0)" ::: "memory");
    __builtin_amdgcn_sched_barrier(0);
    __builtin_amdgcn_s_barrier();           // all waves done -> buffer reusable
    cur ^= 1;
  }
#undef STAGE

  // epilogue: 32x32 C/D layout col=l&31, row=(reg&3)+8*(reg>>2)+4*(l>>5) -> bf16
  unsigned short* Pz = P + (size_t)kz * Mp * Nc;
#pragma unroll
  for (int i = 0; i < 2; ++i) {
#pragma unroll
    for (int j = 0; j < 2; ++j) {
      int colb = n0 + nw * 64 + j * 32 + l31;
#pragma unroll
      for (int r = 0; r < 16; ++r) {
        int row = m0 + mw * 64 + i * 32 + (r & 3) + 8 * (r >> 2) + 4 * h;
        Pz[(size_t)row * Nc + colb] = f2bf(acc[i][j][r]);
      }
    }
  }
}

// ---- split-K reduce (bf16 partials, padded-M slices) -> fp8 image ----
template <int S>
__global__ void reduce_fp8k(const unsigned short* __restrict__ P, const float* __restrict__ bias,
                            unsigned int* __restrict__ outp, long MN4, int nc4) {
  long i = (long)blockIdx.x * blockDim.x + threadIdx.x;
  long stride = (long)gridDim.x * blockDim.x;
  const ushort4* P4 = (const ushort4*)P;
  const float4* B4 = (const float4*)bias;
  for (; i < MN4; i += stride) {
    float vx = 0, vy = 0, vz = 0, vw = 0;
#pragma unroll
    for (int s = 0; s < S; ++s) {
      ushort4 u = P4[s * MN4 + i];
      vx += bf2f(u.x); vy += bf2f(u.y); vz += bf2f(u.z); vw += bf2f(u.w);
    }
    float4 b = B4[i & (nc4 - 1)];
    vx = fmaxf(vx * (1.0f / WSC) + b.x, 0.0f);
    vy = fmaxf(vy * (1.0f / WSC) + b.y, 0.0f);
    vz = fmaxf(vz * (1.0f / WSC) + b.z, 0.0f);
    vw = fmaxf(vw * (1.0f / WSC) + b.w, 0.0f);
    unsigned int r = (unsigned int)__builtin_amdgcn_cvt_pk_fp8_f32(vx, vy, 0, false);
    r = (unsigned int)__builtin_amdgcn_cvt_pk_fp8_f32(vz, vw, (int)r, true);
    int rr = (int)(i >> 8);
    int kb = ((int)i & 255) * 4;
    outp[img_off(rr, kb, REPD / 64) >> 2] = r;
  }
}

// ---- per-row loss, reading GEMM3's 4 bf16 split-K slices + bias directly ----
__global__ void loss_row(const unsigned short* __restrict__ P, const float* __restrict__ bh,
                         const int* __restrict__ labels, const float* __restrict__ tgts,
                         float* __restrict__ nll_v, float* __restrict__ vc_v,
                         float* __restrict__ sl1_v) {
  int r = blockIdx.x;
  int l = threadIdx.x;
  const size_t SL = (size_t)MPAD * NH;
  const unsigned short* p0 = P + (size_t)r * NH;
#define COLV(c) ((bf2f(p0[(c)]) + bf2f(p0[SL + (c)]) + bf2f(p0[2 * SL + (c)]) + \
                  bf2f(p0[3 * SL + (c)])) * (1.0f / WSC) + bh[(c)])
  float v1 = COLV(l);
  float v2 = (l < CC - 64) ? COLV(64 + l) : -3.4e38f;
  float m = fmaxf(v1, v2);
#pragma unroll
  for (int o = 32; o; o >>= 1) m = fmaxf(m, __shfl_xor(m, o));
  float e = __expf(v1 - m) + ((l < CC - 64) ? __expf(v2 - m) : 0.0f);
#pragma unroll
  for (int o = 32; o; o >>= 1) e += __shfl_xor(e, o);
  if (l == 0) {
    float lse = m + __logf(e);
    int lab = labels[r];
    int sl = lab < 0 ? 0 : (lab > CC - 1 ? CC - 1 : lab);
    float valid = (lab >= 0) ? 1.0f : 0.0f;
    nll_v[r] = (lse - COLV(sl)) * valid;
    vc_v[r] = valid;
    float s = 0.0f;
#pragma unroll
    for (int d = 0; d < 4; ++d) {
      float pd = COLV(CC + sl * 4 + d);
      float ad = fabsf(pd - tgts[r * 4 + d]);
      s += (ad < BETA) ? 0.5f * ad * ad / BETA : ad - 0.5f * BETA;
    }
    sl1_v[r] = (lab > 0) ? s : 0.0f;
  }
#undef COLV
}

// ---- deterministic final reduce ----
__global__ void reduce_final(const float* __restrict__ nll_v, const float* __restrict__ vc_v,
                             const float* __restrict__ sl1_v, float* __restrict__ out) {
  __shared__ float s1[256], s2[256], s3[256];
  int t = threadIdx.x;
  float a = 0, b = 0, c = 0;
  for (int i = t; i < RT; i += 256) { a += nll_v[i]; b += vc_v[i]; c += sl1_v[i]; }
  s1[t] = a; s2[t] = b; s3[t] = c;
  __syncthreads();
  for (int o = 128; o; o >>= 1) {
    if (t < o) { s1[t] += s1[t + o]; s2[t] += s2[t + o]; s3[t] += s3[t + o]; }
    __syncthreads();
  }
  if (t == 0) {
    out[0] = s1[0] / fmaxf(s2[0], 1.0f);
    out[1] = s3[0] / (float)RT;
  }
}

extern "C" void kernel_launch(void* const* d_in, const int* in_sizes, int n_in,
                              void* d_out, int out_size, void* d_ws, size_t ws_size,
                              hipStream_t stream) {
  const float* proposals = (const float*)d_in[0];
  const float* gt_boxes  = (const float*)d_in[1];
  const float* features  = (const float*)d_in[2];
  const float* W1   = (const float*)d_in[3];
  const float* b1   = (const float*)d_in[4];
  const float* W2   = (const float*)d_in[5];
  const float* b2   = (const float*)d_in[6];
  const float* Wcls = (const float*)d_in[7];
  const float* bcls = (const float*)d_in[8];
  const float* Wbox = (const float*)d_in[9];
  const float* bbox = (const float*)d_in[10];
  const int* gt_labels = (const int*)d_in[11];
  float* out = (float*)d_out;

  char* ws = (char*)d_ws;
  unsigned char* W1t = (unsigned char*)(ws + O_W1T);
  unsigned char* W2t = (unsigned char*)(ws + O_W2T);
  unsigned char* Wh  = (unsigned char*)(ws + O_WH);
  float* bh          = (float*)(ws + O_BH);
  unsigned char* x1  = (unsigned char*)(ws + O_X1);
  unsigned char* x2  = (unsigned char*)(ws + O_X2);
  int* labels        = (int*)(ws + O_LAB);
  float* tgts        = (float*)(ws + O_TGT);
  float* nll_v       = (float*)(ws + O_NLL);
  float* vc_v        = (float*)(ws + O_VC);
  float* sl1_v       = (float*)(ws + O_SL1);
  unsigned short* part = (unsigned short*)(ws + O_PART);
  unsigned char* feat8 = (unsigned char*)(ws + O_F8);

  // 1. prep: feature fp8 tile-image / weight images / misc
  prep_cv<<<NB_CV, 256, 0, stream>>>(features, feat8);
  prep_w<<<NB_PW, 256, 0, stream>>>(W1, W2, Wcls, Wbox, W1t, W2t, Wh);
  prep_misc<<<NB_MISC, 256, 0, stream>>>(bcls, bbox, proposals, gt_boxes, gt_labels,
                                         Wh, bh, labels, tgts);

  // 2. GEMM1: 128x256, KT=196, split-4 (nkt=49), n_nblk=4, pairs=34*4=136
  //    grid 8*4*17=544 at 2 blocks/CU
  gemm_f8<<<544, 512, 0, stream>>>(feat8, W1t, part, MPAD, REPD, FEATD/64, 49,
                                   4, 34, 136);
  reduce_fp8k<4><<<2048, 256, 0, stream>>>(part, b1, (unsigned int*)x1,
                                           (long)MPAD * REPD / 4, REPD / 4);

  // 3. GEMM2: 128x256, KT=16, split-4 (nkt=4), n_nblk=4, pairs=136 -> grid 544
  gemm_f8<<<544, 512, 0, stream>>>(x1, W2t, part, MPAD, REPD, REPD/64, 4,
                                   4, 34, 136);
  reduce_fp8k<4><<<2048, 256, 0, stream>>>(part, b2, (unsigned int*)x2,
                                           (long)MPAD * REPD / 4, REPD / 4);

  // 4. GEMM3: 128x256, KT=16, split-4 (nkt=4), Nc=512 (n_nblk=2), pairs=136
  //    grid 8*2*17=272
  gemm_f8<<<272, 512, 0, stream>>>(x2, Wh, part, MPAD, NH, REPD/64, 4,
                                   2, 34, 136);

  // 5. losses (loss_row folds GEMM3's 4-slice reduce + bias + 1/WSC)
  loss_row<<<RT, 64, 0, stream>>>(part, bh, labels, tgts, nll_v, vc_v, sl1_v);
  reduce_final<<<1, 256, 0, stream>>>(nll_v, vc_v, sl1_v, out);
}

// Round 10
// 471.995 us; speedup vs baseline: 1.0699x; 1.0699x over previous
//
#include <hip/hip_runtime.h>
#include <cstdint>
#include <cstddef>

// ---- problem constants ----
#define BQ   8
#define NP   512
#define GQ   16
#define PP   528      // NP + GQ
#define RT   4224     // BQ * PP
#define MPAD 4352     // RT padded to 34 row-blocks of 128
#define CC   91
#define FEATD 12544
#define REPD 1024
#define NH   512      // padded head output cols (455 used: 91 cls + 364 box)
#define NHU  455
#define BETA (1.0f/9.0f)
#define WSC  64.0f    // fp8 weight pre-scale (exact pow2; undone in reduce/loss)

typedef float f32x4 __attribute__((ext_vector_type(4)));
typedef int   v8i  __attribute__((ext_vector_type(8)));
typedef float v16f __attribute__((ext_vector_type(16)));

__device__ __forceinline__ unsigned short f2bf(float f) {
  unsigned int x = __float_as_uint(f);
  unsigned int r = (x + 0x7fffu + ((x >> 16) & 1u)) >> 16;
  return (unsigned short)r;
}
__device__ __forceinline__ float bf2f(unsigned short u) {
  return __uint_as_float((unsigned int)u << 16);
}

// async global->LDS DMA, 16 B per lane; HW writes lane L to base + L*16.
__device__ __forceinline__ void ld_lds16(const void* g, void* l) {
  __builtin_amdgcn_global_load_lds(
      (const __attribute__((address_space(1))) void*)g,
      (__attribute__((address_space(3))) void*)l, 16, 0, 0);
}

// ---- tile-image layout --------------------------------------------------
// Image: 128-row x 64-kbyte tile = 8192 B, tiles ordered [rowblk][ktile].
// Within a tile: region (row>>5)&3 (2048 B), then [kc=(kb>>4)&3][r=row&31][16B].
__device__ __forceinline__ size_t img_off(int row, int kb, int KT) {
  return (size_t)((row >> 7) * KT + (kb >> 6)) * 8192
       + (size_t)((((row >> 5) & 3) << 11) + (((kb >> 4) & 3) << 9)
                  + ((row & 31) << 4) + (kb & 15));
}

// ---- workspace layout (bytes) ----
constexpr size_t O_W1T = 0;
constexpr size_t SZ_W1T = (size_t)FEATD * REPD;             // W1^T fp8 image
constexpr size_t O_W2T = O_W1T + SZ_W1T;
constexpr size_t SZ_W2T = (size_t)REPD * REPD;              // W2^T fp8 image
constexpr size_t O_WH  = O_W2T + SZ_W2T;
constexpr size_t SZ_WH = (size_t)NH * REPD;                 // [Wcls|Wbox]^T fp8 image
constexpr size_t O_BH  = O_WH + SZ_WH;
constexpr size_t SZ_BH = (size_t)NH * 4;
constexpr size_t O_X1  = O_BH + SZ_BH;
constexpr size_t SZ_X1 = (size_t)MPAD * REPD;               // x1 fp8 image (padded)
constexpr size_t O_X2  = O_X1 + SZ_X1;                      // x2 fp8 image (padded)
constexpr size_t O_LAB = O_X2 + SZ_X1;
constexpr size_t O_TGT = O_LAB + (size_t)RT * 4;
constexpr size_t O_NLL = O_TGT + (size_t)RT * 16;
constexpr size_t O_VC  = O_NLL + (size_t)RT * 4;
constexpr size_t O_SL1 = O_VC + (size_t)RT * 4;
constexpr size_t O_PART = ((O_SL1 + (size_t)RT * 4) + 255) & ~(size_t)255;
constexpr size_t SZ_PART = (size_t)4 * MPAD * REPD * 2;     // bf16 partials (padded M)
constexpr size_t O_F8 = O_PART + SZ_PART;                   // fp8 feature image, 54.6 MB

// ===== fused prep: feature image + weight images + head/matcher ==========
// One kernel, grid-concatenated (saves 2 launches; pw/misc co-schedule under
// cv's occupancy instead of running after a full drain). Shared mem = union
// (18.4 KB -> 8 blocks/CU).
#define NB_CV ((MPAD/32)*(FEATD/256))    // 136*49 = 6664
#define NBW1 ((REPD/32)*(FEATD/128))     // 3136
#define NBW2 ((REPD/32)*(REPD/128))      // 256
#define NBWC (3*(REPD/128))              // 24
#define NBWB (12*(REPD/128))             // 96
#define NB_PW (NBW1+NBW2+NBWC+NBWB)      // 3512
#define NB_HI 230
#define NB_MT 17
#define NB_MISC (NB_HI+NB_MT)            // 247
#define NB_PREP (NB_CV+NB_PW+NB_MISC)    // 10423

__device__ __forceinline__ void tr128(const float* __restrict__ in, unsigned char* __restrict__ out,
                                      int K, int N, int row_off, int KT,
                                      int bx, int by, int t, float (*tile)[36]) {
  const int n0 = bx * 32, k0 = by * 128;
  const int n4 = t & 7, kr = t >> 3;       // kr 0..31
  if (n0 + 32 <= N) {
#pragma unroll
    for (int i = 0; i < 4; ++i) {
      int k = k0 + kr + i * 32;
      float4 f = *(const float4*)&in[(size_t)k * N + n0 + n4 * 4];
      *(float4*)&tile[kr + i * 32][n4 * 4] = f;
    }
  } else {
#pragma unroll
    for (int i = 0; i < 4; ++i) {
      int k = k0 + kr + i * 32;
#pragma unroll
      for (int j = 0; j < 4; ++j) {
        int n = n0 + n4 * 4 + j;
        tile[kr + i * 32][n4 * 4 + j] = (n < N) ? in[(size_t)k * N + n] : 0.0f;
      }
    }
  }
  __syncthreads();
  const int rn = t & 31, kc = t >> 5;      // kc 0..7 (16 k each)
  const int n = n0 + rn;
  if (n < N) {
    unsigned int pk[4];
#pragma unroll
    for (int q = 0; q < 4; ++q) {
      float f0 = tile[kc * 16 + q * 4 + 0][rn] * WSC;
      float f1 = tile[kc * 16 + q * 4 + 1][rn] * WSC;
      float f2 = tile[kc * 16 + q * 4 + 2][rn] * WSC;
      float f3 = tile[kc * 16 + q * 4 + 3][rn] * WSC;
      unsigned int r = (unsigned int)__builtin_amdgcn_cvt_pk_fp8_f32(f0, f1, 0, false);
      pk[q] = (unsigned int)__builtin_amdgcn_cvt_pk_fp8_f32(f2, f3, (int)r, true);
    }
    int4 v; v.x = (int)pk[0]; v.y = (int)pk[1]; v.z = (int)pk[2]; v.w = (int)pk[3];
    *(int4*)&out[img_off(n + row_off, k0 + kc * 16, KT)] = v;
  }
}

__global__ void prep(const float* __restrict__ feat, unsigned char* __restrict__ feat8,
                     const float* __restrict__ W1, const float* __restrict__ W2,
                     const float* __restrict__ Wcls, const float* __restrict__ Wbox,
                     const float* __restrict__ bcls, const float* __restrict__ bbox,
                     const float* __restrict__ proposals, const float* __restrict__ gt_boxes,
                     const int* __restrict__ gt_labels,
                     unsigned char* __restrict__ W1t, unsigned char* __restrict__ W2t,
                     unsigned char* __restrict__ Wh, float* __restrict__ bh,
                     int* __restrict__ labels, float* __restrict__ tgts) {
  __shared__ __align__(16) char smem[128 * 36 * 4];   // union: cv lb (8448) | w tile (18432)
  int b = blockIdx.x, t = threadIdx.x;
  if (b < NB_CV) {
    // contiguous-read feature convert (R8-proven): every read instr = 1024
    // contiguous bytes of one row; LDS rows padded to 264 B; dense 1-KB
    // copy-out per instruction.
    unsigned char* lb = (unsigned char*)smem;
    const int yb = b / (FEATD / 256), kc4 = b % (FEATD / 256);
    const int w = t >> 6, L = t & 63;
    const int row0 = yb * 32;
    if (row0 < RT) {
#pragma unroll
      for (int i = 0; i < 8; ++i) {
        int r = w * 8 + i;
        float4 f = *(const float4*)(feat + (size_t)(row0 + r) * FEATD + kc4 * 256 + L * 4);
        unsigned int pk = (unsigned int)__builtin_amdgcn_cvt_pk_fp8_f32(f.x, f.y, 0, false);
        pk = (unsigned int)__builtin_amdgcn_cvt_pk_fp8_f32(f.z, f.w, (int)pk, true);
        *(unsigned int*)&lb[r * 264 + L * 4] = pk;
      }
    } else {                               // pad rows 4224..4351 -> zeros
#pragma unroll
      for (int i = 0; i < 8; ++i)
        *(unsigned int*)&lb[(w * 8 + i) * 264 + L * 4] = 0u;
    }
    __syncthreads();
    const size_t base = ((size_t)(yb >> 2) * (FEATD / 64) + kc4 * 4) * 8192
                      + (size_t)(yb & 3) * 2048;
#pragma unroll
    for (int q = 0; q < 2; ++q) {
      int s = t + 256 * q;
      int tile = s >> 7, kc = (s >> 5) & 3, r = s & 31;
      int4 v = *(const int4*)&lb[r * 264 + tile * 64 + kc * 16];
      *(int4*)&feat8[base + (size_t)tile * 8192 + kc * 512 + r * 16] = v;
    }
    return;
  }
  b -= NB_CV;
  if (b < NB_PW) {
    float (*tile)[36] = (float (*)[36])smem;
    if (b < NBW1) { tr128(W1, W1t, FEATD, REPD, 0, FEATD/64, b % 32, b / 32, t, tile); return; }
    b -= NBW1;
    if (b < NBW2) { tr128(W2, W2t, REPD, REPD, 0, REPD/64, b % 32, b / 32, t, tile); return; }
    b -= NBW2;
    if (b < NBWC) { tr128(Wcls, Wh, REPD, CC, 0, REPD/64, b % 3, b / 3, t, tile); return; }
    b -= NBWC;
    tr128(Wbox, Wh, REPD, 4 * CC, CC, REPD/64, b % 12, b / 12, t, tile);
    return;
  }
  b -= NB_PW;
  if (b < NB_HI) {
    int idx = b * 256 + t;
    const int npad = (NH - NHU) * REPD;   // 58368 fp8 zeros (rows 455..511)
    if (idx < npad) {
      int row = NHU + (idx >> 10), k = idx & 1023;
      Wh[img_off(row, k, REPD/64)] = 0;
    } else {
      int i2 = idx - npad;
      if (i2 < NH) bh[i2] = (i2 < CC) ? bcls[i2] : (i2 < NHU ? bbox[i2 - CC] : 0.0f);
    }
    return;
  }
  b -= NB_HI;
  // ---- matcher + encode (exact fp32) ----
  int r = b * 256 + t;
  if (r >= RT) return;
  int bi_ = r / PP, p = r % PP;
  float x0, y0, x1, y1;
  if (p < NP) {
    const float* qq = proposals + ((size_t)bi_ * NP + p) * 4;
    x0 = qq[0]; y0 = qq[1]; x1 = qq[2]; y1 = qq[3];
  } else {
    const float* qq = gt_boxes + ((size_t)bi_ * GQ + (p - NP)) * 4;
    x0 = qq[0]; y0 = qq[1]; x1 = qq[2]; y1 = qq[3];
  }
  float ap = (x1 - x0) * (y1 - y0);
  float best = -1.0f; int bg = 0;
#pragma unroll
  for (int g = 0; g < GQ; ++g) {
    const float* gb = gt_boxes + ((size_t)bi_ * GQ + g) * 4;
    float gx0 = gb[0], gy0 = gb[1], gx1 = gb[2], gy1 = gb[3];
    float ag = (gx1 - gx0) * (gy1 - gy0);
    float iw = fmaxf(fminf(gx1, x1) - fmaxf(gx0, x0), 0.0f);
    float ih = fmaxf(fminf(gy1, y1) - fmaxf(gy0, y0), 0.0f);
    float inter = iw * ih;
    float iou = inter / (ag + ap - inter);
    if (iou > best) { best = iou; bg = g; }   // strict > keeps first max (jnp.argmax)
  }
  int lab = gt_labels[bi_ * GQ + bg];
  if (best < 0.5f) lab = 0;    // FG==BG==0.5 -> ignore band empty
  labels[r] = lab;
  const float* gb = gt_boxes + ((size_t)bi_ * GQ + bg) * 4;
  float ew = x1 - x0, eh = y1 - y0;
  float ex = x0 + 0.5f * ew, ey = y0 + 0.5f * eh;
  float gw = gb[2] - gb[0], gh = gb[3] - gb[1];
  float gx = gb[0] + 0.5f * gw, gy = gb[1] + 0.5f * gh;
  tgts[r * 4 + 0] = 10.0f * (gx - ex) / ew;
  tgts[r * 4 + 1] = 10.0f * (gy - ey) / eh;
  tgts[r * 4 + 2] = 5.0f * logf(gw / ew);
  tgts[r * 4 + 3] = 5.0f * logf(gh / eh);
}

// ---- MX-scaled fp8 GEMM on tile images: 128x128, BK=64, dbuf, vmcnt(4) ----
// R8-proven config (476 us best). 4 blocks/CU is load-bearing (R9: 2 blocks/CU
// lost 29 us despite -25% staged bytes). Do not change geometry without
// re-checking VGPR budget (R7 spill lesson).
__global__ __launch_bounds__(256, 4)
void gemm_f8(const unsigned char* __restrict__ Aimg, const unsigned char* __restrict__ Bimg,
             unsigned short* __restrict__ P, int Mp, int Nc, int KT, int nkt,
             int n_nblk, int n_my, int npairs) {
  __shared__ unsigned char As[2 * 8192];
  __shared__ unsigned char Bs[2 * 8192];

  const int g = blockIdx.x;
  const int xcd = g & 7;
  const int kix = g >> 3;
  const int n  = kix % n_nblk;
  const int pi = kix / n_nblk;
  const int p  = pi * 8 + xcd;
  if (p >= npairs) return;                 // uniform dummy exit, before any barrier
  const int y  = p % n_my;
  const int kz = p / n_my;
  const int m0 = y * 128, n0 = n * 128;

  const int tid = threadIdx.x;
  const int w = tid >> 6, L = tid & 63;
  const int l31 = L & 31, h = L >> 5;
  const int wr = (w >> 1) * 64, wc = (w & 1) * 64;

  const int kt0 = kz * nkt;
  const unsigned char* gA = Aimg + ((size_t)y * KT + kt0) * 8192 + w * 2048 + L * 16;
  const unsigned char* gB = Bimg + ((size_t)n * KT + kt0) * 8192 + w * 2048 + L * 16;
  const int lw = w * 2048;                 // wave w stages region w

#define STAGE(it, bufo) do {                                    \
    const size_t _go = (size_t)(it) * 8192;                     \
    ld_lds16(gA + _go,        &As[(bufo) + lw]);                \
    ld_lds16(gA + _go + 1024, &As[(bufo) + lw + 1024]);         \
    ld_lds16(gB + _go,        &Bs[(bufo) + lw]);                \
    ld_lds16(gB + _go + 1024, &Bs[(bufo) + lw + 1024]);         \
  } while (0)

  int aoff[2], boff[2];
#pragma unroll
  for (int i = 0; i < 2; ++i) {
    aoff[i] = (((w >> 1) * 2 + i) << 11) + (h << 10) + (l31 << 4);
    boff[i] = (((w & 1) * 2 + i) << 11) + (h << 10) + (l31 << 4);
  }

  STAGE(0, 0);                              // prologue: tile 0 -> buffer 0

  v16f acc[2][2] = {};
  int cur = 0;
  for (int it = 0; it < nkt; ++it) {
    const int cb = cur << 13;
    if (it + 1 < nkt) {
      STAGE(it + 1, cb ^ 8192);             // next tile's 4 DMA stay in flight
      asm volatile("s_waitcnt vmcnt(4)" ::: "memory");
    } else {
      asm volatile("s_waitcnt vmcnt(0)" ::: "memory");
    }
    __builtin_amdgcn_sched_barrier(0);
    __builtin_amdgcn_s_barrier();           // tile staged for all waves

    v8i a[2], b[2];
#pragma unroll
    for (int i = 0; i < 2; ++i) {
      int4 alo = *(const int4*)&As[cb + aoff[i]];
      int4 ahi = *(const int4*)&As[cb + aoff[i] + 512];
      a[i] = (v8i){alo.x, alo.y, alo.z, alo.w, ahi.x, ahi.y, ahi.z, ahi.w};
      int4 blo = *(const int4*)&Bs[cb + boff[i]];
      int4 bhi = *(const int4*)&Bs[cb + boff[i] + 512];
      b[i] = (v8i){blo.x, blo.y, blo.z, blo.w, bhi.x, bhi.y, bhi.z, bhi.w};
    }
#pragma unroll
    for (int i = 0; i < 2; ++i)
#pragma unroll
      for (int j = 0; j < 2; ++j)
        acc[i][j] = __builtin_amdgcn_mfma_scale_f32_32x32x64_f8f6f4(
            a[i], b[j], acc[i][j], 0, 0, 0, 127, 0, 127);  // fp8/fp8, scales=2^0

    asm volatile("s_waitcnt lgkmcnt(0)" ::: "memory");
    __builtin_amdgcn_sched_barrier(0);
    __builtin_amdgcn_s_barrier();           // all waves done -> buffer reusable
    cur ^= 1;
  }
#undef STAGE

  // epilogue: 32x32 C/D layout col=l&31, row=(reg&3)+8*(reg>>2)+4*(l>>5) -> bf16
  unsigned short* Pz = P + (size_t)kz * Mp * Nc;
#pragma unroll
  for (int i = 0; i < 2; ++i) {
#pragma unroll
    for (int j = 0; j < 2; ++j) {
      int colb = n0 + wc + j * 32 + l31;
#pragma unroll
      for (int r = 0; r < 16; ++r) {
        int row = m0 + wr + i * 32 + (r & 3) + 8 * (r >> 2) + 4 * h;
        Pz[(size_t)row * Nc + colb] = f2bf(acc[i][j][r]);
      }
    }
  }
}

// ---- split-K reduce (bf16 partials, padded-M slices) -> fp8 image ----
template <int S>
__global__ void reduce_fp8k(const unsigned short* __restrict__ P, const float* __restrict__ bias,
                            unsigned int* __restrict__ outp, long MN4, int nc4) {
  long i = (long)blockIdx.x * blockDim.x + threadIdx.x;
  long stride = (long)gridDim.x * blockDim.x;
  const ushort4* P4 = (const ushort4*)P;
  const float4* B4 = (const float4*)bias;
  for (; i < MN4; i += stride) {
    float vx = 0, vy = 0, vz = 0, vw = 0;
#pragma unroll
    for (int s = 0; s < S; ++s) {
      ushort4 u = P4[s * MN4 + i];
      vx += bf2f(u.x); vy += bf2f(u.y); vz += bf2f(u.z); vw += bf2f(u.w);
    }
    float4 b = B4[i & (nc4 - 1)];
    vx = fmaxf(vx * (1.0f / WSC) + b.x, 0.0f);
    vy = fmaxf(vy * (1.0f / WSC) + b.y, 0.0f);
    vz = fmaxf(vz * (1.0f / WSC) + b.z, 0.0f);
    vw = fmaxf(vw * (1.0f / WSC) + b.w, 0.0f);
    unsigned int r = (unsigned int)__builtin_amdgcn_cvt_pk_fp8_f32(vx, vy, 0, false);
    r = (unsigned int)__builtin_amdgcn_cvt_pk_fp8_f32(vz, vw, (int)r, true);
    int rr = (int)(i >> 8);
    int kb = ((int)i & 255) * 4;
    outp[img_off(rr, kb, REPD / 64) >> 2] = r;
  }
}

// ---- per-row loss, reading GEMM3's 4 bf16 split-K slices + bias directly ----
__global__ void loss_row(const unsigned short* __restrict__ P, const float* __restrict__ bh,
                         const int* __restrict__ labels, const float* __restrict__ tgts,
                         float* __restrict__ nll_v, float* __restrict__ vc_v,
                         float* __restrict__ sl1_v) {
  int r = blockIdx.x;
  int l = threadIdx.x;
  const size_t SL = (size_t)MPAD * NH;
  const unsigned short* p0 = P + (size_t)r * NH;
#define COLV(c) ((bf2f(p0[(c)]) + bf2f(p0[SL + (c)]) + bf2f(p0[2 * SL + (c)]) + \
                  bf2f(p0[3 * SL + (c)])) * (1.0f / WSC) + bh[(c)])
  float v1 = COLV(l);
  float v2 = (l < CC - 64) ? COLV(64 + l) : -3.4e38f;
  float m = fmaxf(v1, v2);
#pragma unroll
  for (int o = 32; o; o >>= 1) m = fmaxf(m, __shfl_xor(m, o));
  float e = __expf(v1 - m) + ((l < CC - 64) ? __expf(v2 - m) : 0.0f);
#pragma unroll
  for (int o = 32; o; o >>= 1) e += __shfl_xor(e, o);
  if (l == 0) {
    float lse = m + __logf(e);
    int lab = labels[r];
    int sl = lab < 0 ? 0 : (lab > CC - 1 ? CC - 1 : lab);
    float valid = (lab >= 0) ? 1.0f : 0.0f;
    nll_v[r] = (lse - COLV(sl)) * valid;
    vc_v[r] = valid;
    float s = 0.0f;
#pragma unroll
    for (int d = 0; d < 4; ++d) {
      float pd = COLV(CC + sl * 4 + d);
      float ad = fabsf(pd - tgts[r * 4 + d]);
      s += (ad < BETA) ? 0.5f * ad * ad / BETA : ad - 0.5f * BETA;
    }
    sl1_v[r] = (lab > 0) ? s : 0.0f;
  }
#undef COLV
}

// ---- deterministic final reduce ----
__global__ void reduce_final(const float* __restrict__ nll_v, const float* __restrict__ vc_v,
                             const float* __restrict__ sl1_v, float* __restrict__ out) {
  __shared__ float s1[256], s2[256], s3[256];
  int t = threadIdx.x;
  float a = 0, b = 0, c = 0;
  for (int i = t; i < RT; i += 256) { a += nll_v[i]; b += vc_v[i]; c += sl1_v[i]; }
  s1[t] = a; s2[t] = b; s3[t] = c;
  __syncthreads();
  for (int o = 128; o; o >>= 1) {
    if (t < o) { s1[t] += s1[t + o]; s2[t] += s2[t + o]; s3[t] += s3[t + o]; }
    __syncthreads();
  }
  if (t == 0) {
    out[0] = s1[0] / fmaxf(s2[0], 1.0f);
    out[1] = s3[0] / (float)RT;
  }
}

extern "C" void kernel_launch(void* const* d_in, const int* in_sizes, int n_in,
                              void* d_out, int out_size, void* d_ws, size_t ws_size,
                              hipStream_t stream) {
  const float* proposals = (const float*)d_in[0];
  const float* gt_boxes  = (const float*)d_in[1];
  const float* features  = (const float*)d_in[2];
  const float* W1   = (const float*)d_in[3];
  const float* b1   = (const float*)d_in[4];
  const float* W2   = (const float*)d_in[5];
  const float* b2   = (const float*)d_in[6];
  const float* Wcls = (const float*)d_in[7];
  const float* bcls = (const float*)d_in[8];
  const float* Wbox = (const float*)d_in[9];
  const float* bbox = (const float*)d_in[10];
  const int* gt_labels = (const int*)d_in[11];
  float* out = (float*)d_out;

  char* ws = (char*)d_ws;
  unsigned char* W1t = (unsigned char*)(ws + O_W1T);
  unsigned char* W2t = (unsigned char*)(ws + O_W2T);
  unsigned char* Wh  = (unsigned char*)(ws + O_WH);
  float* bh          = (float*)(ws + O_BH);
  unsigned char* x1  = (unsigned char*)(ws + O_X1);
  unsigned char* x2  = (unsigned char*)(ws + O_X2);
  int* labels        = (int*)(ws + O_LAB);
  float* tgts        = (float*)(ws + O_TGT);
  float* nll_v       = (float*)(ws + O_NLL);
  float* vc_v        = (float*)(ws + O_VC);
  float* sl1_v       = (float*)(ws + O_SL1);
  unsigned short* part = (unsigned short*)(ws + O_PART);
  unsigned char* feat8 = (unsigned char*)(ws + O_F8);

  // 1. fused prep: feature image + weight images + head/matcher (one launch)
  prep<<<NB_PREP, 256, 0, stream>>>(features, feat8, W1, W2, Wcls, Wbox,
                                    bcls, bbox, proposals, gt_boxes, gt_labels,
                                    W1t, W2t, Wh, bh, labels, tgts);

  // 2. GEMM1: 128^2, KT=196, split-4 (nkt=49), pairs=34*4=136 -> grid 8*8*17=1088
  gemm_f8<<<1088, 256, 0, stream>>>(feat8, W1t, part, MPAD, REPD, FEATD/64, 49,
                                    8, 34, 136);
  reduce_fp8k<4><<<2048, 256, 0, stream>>>(part, b1, (unsigned int*)x1,
                                           (long)MPAD * REPD / 4, REPD / 4);

  // 3. GEMM2: 128^2, KT=16, split-2 (nkt=8), pairs=68 -> grid 8*8*9=576
  gemm_f8<<<576, 256, 0, stream>>>(x1, W2t, part, MPAD, REPD, REPD/64, 8,
                                   8, 34, 68);
  reduce_fp8k<2><<<2048, 256, 0, stream>>>(part, b2, (unsigned int*)x2,
                                           (long)MPAD * REPD / 4, REPD / 4);

  // 4. GEMM3: 128^2, KT=16, split-4 (nkt=4), Nc=512 (4 n-blocks), pairs=136 -> grid 544
  gemm_f8<<<544, 256, 0, stream>>>(x2, Wh, part, MPAD, NH, REPD/64, 4,
                                   4, 34, 136);

  // 5. losses (loss_row folds GEMM3's 4-slice reduce + bias + 1/WSC)
  loss_row<<<RT, 64, 0, stream>>>(part, bh, labels, tgts, nll_v, vc_v, sl1_v);
  reduce_final<<<1, 256, 0, stream>>>(nll_v, vc_v, sl1_v, out);
}